// Round 1
// baseline (415.531 us; speedup 1.0000x reference)
//
#include <hip/hip_runtime.h>

#define N_NODES 50000
#define N_EDGES 800000
#define D 128

// ---------------------------------------------------------------------------
// LayerNorm + ReLU + dropout-mask.  One wave (64 lanes) per node, float2/lane.
// ---------------------------------------------------------------------------
__global__ __launch_bounds__(256) void ln_kernel(
    const float* __restrict__ x, const float* __restrict__ mask,
    const float* __restrict__ gamma, const float* __restrict__ beta,
    float* __restrict__ h) {
  const int l = threadIdx.x & 63;
  const int n = blockIdx.x * 4 + (threadIdx.x >> 6);
  const float2 xv = ((const float2*)x)[(size_t)n * 64 + l];
  float s = xv.x + xv.y;
  float q = xv.x * xv.x + xv.y * xv.y;
#pragma unroll
  for (int m = 1; m < 64; m <<= 1) {
    s += __shfl_xor(s, m);
    q += __shfl_xor(q, m);
  }
  const float mean = s * (1.0f / 128.0f);
  const float var = q * (1.0f / 128.0f) - mean * mean;
  const float rs = rsqrtf(var + 1e-5f);
  const float2 gv = ((const float2*)gamma)[l];
  const float2 bv = ((const float2*)beta)[l];
  const float2 mv = ((const float2*)mask)[(size_t)n * 64 + l];
  float2 hv;
  hv.x = fmaxf((xv.x - mean) * rs * gv.x + bv.x, 0.0f) * mv.x;
  hv.y = fmaxf((xv.y - mean) * rs * gv.y + bv.y, 0.0f) * mv.y;
  ((float2*)h)[(size_t)n * 64 + l] = hv;
}

// ---------------------------------------------------------------------------
// Transpose/stack weights: wt[k][d] with d<128 -> w_l[d][k], d>=128 -> w_r.
// ---------------------------------------------------------------------------
__global__ __launch_bounds__(256) void wt_kernel(
    const float* __restrict__ w_l, const float* __restrict__ w_r,
    float* __restrict__ wt) {
  const int i = blockIdx.x * 256 + threadIdx.x;  // 128*256 total
  const int k = i >> 8;
  const int d = i & 255;
  wt[i] = (d < D) ? w_l[d * D + k] : w_r[(d - D) * D + k];
}

// ---------------------------------------------------------------------------
// Fused GEMM: g = h @ w_l^T, r = h @ w_r^T + b_l.
// Tile: 32 nodes x 256 outs per 256-thread block; K=128 in chunks of 32.
// Thread (tx = t&31, ty = t>>5) computes 4 nodes x (4 g-outs + 4 r-outs).
// ---------------------------------------------------------------------------
__global__ __launch_bounds__(256) void gemm_kernel(
    const float* __restrict__ h, const float* __restrict__ wt,
    const float* __restrict__ b_l, float* __restrict__ g,
    float* __restrict__ r) {
  __shared__ __align__(16) float As[32][32];    // [kk][node]
  __shared__ __align__(16) float Ws[32 * 256];  // [kk][d]
  const int t = threadIdx.x;
  const int tx = t & 31;
  const int ty = t >> 5;
  const int nb = blockIdx.x * 32;
  float acc[4][8];
#pragma unroll
  for (int i = 0; i < 4; ++i)
#pragma unroll
    for (int j = 0; j < 8; ++j) acc[i][j] = 0.0f;

  for (int c = 0; c < 4; ++c) {
    const int k0 = c * 32;
    // Stage A (transposed into LDS): thread loads float4 along k.
    {
      const int node = t >> 3;
      const int kk = (t & 7) * 4;
      int n = nb + node;
      if (n >= N_NODES) n = N_NODES - 1;  // clamp; store is guarded later
      const float4 v = *(const float4*)(h + (size_t)n * D + k0 + kk);
      As[kk + 0][node] = v.x;
      As[kk + 1][node] = v.y;
      As[kk + 2][node] = v.z;
      As[kk + 3][node] = v.w;
    }
    // Stage W chunk: contiguous 32*256 floats.
    {
      const float4* src = (const float4*)(wt + (size_t)k0 * 256);
      float4* dstp = (float4*)(&Ws[0]);
#pragma unroll
      for (int i = 0; i < 8; ++i) dstp[t + 256 * i] = src[t + 256 * i];
    }
    __syncthreads();
#pragma unroll
    for (int kk = 0; kk < 32; ++kk) {
      const float4 a = *(const float4*)(&As[kk][ty * 4]);
      const float4 w0 = *(const float4*)(&Ws[kk * 256 + tx * 4]);
      const float4 w1 = *(const float4*)(&Ws[kk * 256 + 128 + tx * 4]);
      const float av[4] = {a.x, a.y, a.z, a.w};
#pragma unroll
      for (int i = 0; i < 4; ++i) {
        acc[i][0] += av[i] * w0.x;
        acc[i][1] += av[i] * w0.y;
        acc[i][2] += av[i] * w0.z;
        acc[i][3] += av[i] * w0.w;
        acc[i][4] += av[i] * w1.x;
        acc[i][5] += av[i] * w1.y;
        acc[i][6] += av[i] * w1.z;
        acc[i][7] += av[i] * w1.w;
      }
    }
    __syncthreads();
  }
  // Epilogue: g gets w_l result, r gets w_r result + bias.
  const float4 bv = ((const float4*)b_l)[tx];
#pragma unroll
  for (int i = 0; i < 4; ++i) {
    const int n = nb + ty * 4 + i;
    if (n < N_NODES) {
      float4 gv, rv;
      gv.x = acc[i][0]; gv.y = acc[i][1]; gv.z = acc[i][2]; gv.w = acc[i][3];
      rv.x = acc[i][4] + bv.x; rv.y = acc[i][5] + bv.y;
      rv.z = acc[i][6] + bv.z; rv.w = acc[i][7] + bv.w;
      *(float4*)(g + (size_t)n * D + tx * 4) = gv;
      *(float4*)(r + (size_t)n * D + tx * 4) = rv;
    }
  }
}

// ---------------------------------------------------------------------------
// CSR build: degree histogram -> exclusive scan -> slot scatter.
// ---------------------------------------------------------------------------
__global__ __launch_bounds__(256) void hist_kernel(const int* __restrict__ ei,
                                                   int* __restrict__ deg) {
  const int e = blockIdx.x * 256 + threadIdx.x;
  if (e < N_EDGES) atomicAdd(&deg[ei[N_EDGES + e]], 1);
}

__global__ __launch_bounds__(1024) void scan_kernel(
    const int* __restrict__ deg, int* __restrict__ offsets,
    int* __restrict__ cursor) {
  __shared__ int sm[1024];
  const int t = threadIdx.x;
  const int C = (N_NODES + 1023) / 1024;  // 49
  const int i0 = t * C;
  const int i1 = min(i0 + C, N_NODES);
  int part = 0;
  for (int i = i0; i < i1; ++i) part += deg[i];
  sm[t] = part;
  __syncthreads();
  for (int ofs = 1; ofs < 1024; ofs <<= 1) {
    int v = sm[t];
    if (t >= ofs) v += sm[t - ofs];
    __syncthreads();
    sm[t] = v;
    __syncthreads();
  }
  int run = sm[t] - part;  // exclusive prefix
  for (int i = i0; i < i1; ++i) {
    offsets[i] = run;
    cursor[i] = run;
    run += deg[i];
  }
  if (i1 == N_NODES) offsets[N_NODES] = run;  // == E
}

__global__ __launch_bounds__(256) void scatter_kernel(
    const int* __restrict__ ei, int* __restrict__ cursor,
    int* __restrict__ csr) {
  const int e = blockIdx.x * 256 + threadIdx.x;
  if (e < N_EDGES) {
    const int src = ei[e];
    const int dst = ei[N_EDGES + e];
    const int pos = atomicAdd(&cursor[dst], 1);
    csr[pos] = src;
  }
}

// ---------------------------------------------------------------------------
// Mean-aggregate g rows per dst node (one wave per node), fuse + r -> out.
// Indices loaded 64-wide and broadcast with shfl so row loads pipeline.
// ---------------------------------------------------------------------------
__global__ __launch_bounds__(256) void agg_kernel(
    const int* __restrict__ offsets, const int* __restrict__ csr,
    const float* __restrict__ g, const float* __restrict__ r,
    float* __restrict__ out) {
  const int l = threadIdx.x & 63;
  const int n = blockIdx.x * 4 + (threadIdx.x >> 6);
  const int s = offsets[n];
  const int e = offsets[n + 1];
  float2 acc = make_float2(0.0f, 0.0f);
  const float2* g2 = (const float2*)g;
  for (int base = s; base < e; base += 64) {
    const int rem = e - base;
    int idx = 0;
    if (l < rem) idx = csr[base + l];
    const int cnt = rem < 64 ? rem : 64;
    for (int j = 0; j < cnt; ++j) {
      const int src = __shfl(idx, j);
      const float2 v = g2[(size_t)src * 64 + l];
      acc.x += v.x;
      acc.y += v.y;
    }
  }
  const float inv = 1.0f / fmaxf((float)(e - s), 1.0f);
  const float2 rv = ((const float2*)r)[(size_t)n * 64 + l];
  float2 o;
  o.x = fmaf(acc.x, inv, rv.x);
  o.y = fmaf(acc.y, inv, rv.y);
  ((float2*)out)[(size_t)n * 64 + l] = o;
}

// ---------------------------------------------------------------------------
extern "C" void kernel_launch(void* const* d_in, const int* in_sizes, int n_in,
                              void* d_out, int out_size, void* d_ws,
                              size_t ws_size, hipStream_t stream) {
  const float* x = (const float*)d_in[0];
  const int* ei = (const int*)d_in[1];  // [2,E] flat: src [0,E), dst [E,2E)
  const float* mask = (const float*)d_in[2];
  const float* gamma = (const float*)d_in[3];
  const float* beta = (const float*)d_in[4];
  const float* w_l = (const float*)d_in[5];
  const float* b_l = (const float*)d_in[6];
  const float* w_r = (const float*)d_in[7];
  float* out = (float*)d_out;

  char* ws = (char*)d_ws;
  size_t off = 0;
  auto alloc = [&](size_t bytes) {
    char* p = ws + off;
    off += (bytes + 255) & ~(size_t)255;
    return p;
  };
  float* h = (float*)alloc((size_t)N_NODES * D * sizeof(float));
  float* g = (float*)alloc((size_t)N_NODES * D * sizeof(float));
  float* r = (float*)alloc((size_t)N_NODES * D * sizeof(float));
  float* wt = (float*)alloc((size_t)2 * D * D * sizeof(float));
  int* deg = (int*)alloc((size_t)N_NODES * sizeof(int));
  int* offsets = (int*)alloc((size_t)(N_NODES + 1) * sizeof(int));
  int* cursor = (int*)alloc((size_t)N_NODES * sizeof(int));
  int* csr = (int*)alloc((size_t)N_EDGES * sizeof(int));

  hipMemsetAsync(deg, 0, (size_t)N_NODES * sizeof(int), stream);
  wt_kernel<<<(2 * D * D) / 256, 256, 0, stream>>>(w_l, w_r, wt);
  ln_kernel<<<N_NODES / 4, 256, 0, stream>>>(x, mask, gamma, beta, h);
  gemm_kernel<<<(N_NODES + 31) / 32, 256, 0, stream>>>(h, wt, b_l, g, r);
  hist_kernel<<<N_EDGES / 256, 256, 0, stream>>>(ei, deg);
  scan_kernel<<<1, 1024, 0, stream>>>(deg, offsets, cursor);
  scatter_kernel<<<N_EDGES / 256, 256, 0, stream>>>(ei, cursor, csr);
  agg_kernel<<<N_NODES / 4, 256, 0, stream>>>(offsets, csr, g, r, out);
}

// Round 2
// 320.394 us; speedup vs baseline: 1.2969x; 1.2969x over previous
//
#include <hip/hip_runtime.h>

#define N_NODES 50000
#define N_EDGES 800000
#define D 128
#define NB_SCAN ((N_NODES + 255) / 256)  // 196

// ---------------------------------------------------------------------------
// LayerNorm + ReLU + dropout-mask.  One wave (64 lanes) per node, float2/lane.
// ---------------------------------------------------------------------------
__global__ __launch_bounds__(256) void ln_kernel(
    const float* __restrict__ x, const float* __restrict__ mask,
    const float* __restrict__ gamma, const float* __restrict__ beta,
    float* __restrict__ h) {
  const int l = threadIdx.x & 63;
  const int n = blockIdx.x * 4 + (threadIdx.x >> 6);
  const float2 xv = ((const float2*)x)[(size_t)n * 64 + l];
  float s = xv.x + xv.y;
  float q = xv.x * xv.x + xv.y * xv.y;
#pragma unroll
  for (int m = 1; m < 64; m <<= 1) {
    s += __shfl_xor(s, m);
    q += __shfl_xor(q, m);
  }
  const float mean = s * (1.0f / 128.0f);
  const float var = q * (1.0f / 128.0f) - mean * mean;
  const float rs = rsqrtf(var + 1e-5f);
  const float2 gv = ((const float2*)gamma)[l];
  const float2 bv = ((const float2*)beta)[l];
  const float2 mv = ((const float2*)mask)[(size_t)n * 64 + l];
  float2 hv;
  hv.x = fmaxf((xv.x - mean) * rs * gv.x + bv.x, 0.0f) * mv.x;
  hv.y = fmaxf((xv.y - mean) * rs * gv.y + bv.y, 0.0f) * mv.y;
  ((float2*)h)[(size_t)n * 64 + l] = hv;
}

// ---------------------------------------------------------------------------
// Transpose/stack weights: wt[k][d] with d<128 -> w_l[d][k], d>=128 -> w_r.
// ---------------------------------------------------------------------------
__global__ __launch_bounds__(256) void wt_kernel(
    const float* __restrict__ w_l, const float* __restrict__ w_r,
    float* __restrict__ wt) {
  const int i = blockIdx.x * 256 + threadIdx.x;  // 128*256 total
  const int k = i >> 8;
  const int d = i & 255;
  wt[i] = (d < D) ? w_l[d * D + k] : w_r[(d - D) * D + k];
}

// ---------------------------------------------------------------------------
// Fused GEMM: g = h @ w_l^T, r = h @ w_r^T + b_l.
// Tile: 32 nodes x 256 outs per 256-thread block; K=128 in chunks of 32.
// ---------------------------------------------------------------------------
__global__ __launch_bounds__(256) void gemm_kernel(
    const float* __restrict__ h, const float* __restrict__ wt,
    const float* __restrict__ b_l, float* __restrict__ g,
    float* __restrict__ r) {
  __shared__ __align__(16) float As[32][32];    // [kk][node]
  __shared__ __align__(16) float Ws[32 * 256];  // [kk][d]
  const int t = threadIdx.x;
  const int tx = t & 31;
  const int ty = t >> 5;
  const int nb = blockIdx.x * 32;
  float acc[4][8];
#pragma unroll
  for (int i = 0; i < 4; ++i)
#pragma unroll
    for (int j = 0; j < 8; ++j) acc[i][j] = 0.0f;

  for (int c = 0; c < 4; ++c) {
    const int k0 = c * 32;
    {
      const int node = t >> 3;
      const int kk = (t & 7) * 4;
      int n = nb + node;
      if (n >= N_NODES) n = N_NODES - 1;  // clamp; store is guarded later
      const float4 v = *(const float4*)(h + (size_t)n * D + k0 + kk);
      As[kk + 0][node] = v.x;
      As[kk + 1][node] = v.y;
      As[kk + 2][node] = v.z;
      As[kk + 3][node] = v.w;
    }
    {
      const float4* src = (const float4*)(wt + (size_t)k0 * 256);
      float4* dstp = (float4*)(&Ws[0]);
#pragma unroll
      for (int i = 0; i < 8; ++i) dstp[t + 256 * i] = src[t + 256 * i];
    }
    __syncthreads();
#pragma unroll
    for (int kk = 0; kk < 32; ++kk) {
      const float4 a = *(const float4*)(&As[kk][ty * 4]);
      const float4 w0 = *(const float4*)(&Ws[kk * 256 + tx * 4]);
      const float4 w1 = *(const float4*)(&Ws[kk * 256 + 128 + tx * 4]);
      const float av[4] = {a.x, a.y, a.z, a.w};
#pragma unroll
      for (int i = 0; i < 4; ++i) {
        acc[i][0] += av[i] * w0.x;
        acc[i][1] += av[i] * w0.y;
        acc[i][2] += av[i] * w0.z;
        acc[i][3] += av[i] * w0.w;
        acc[i][4] += av[i] * w1.x;
        acc[i][5] += av[i] * w1.y;
        acc[i][6] += av[i] * w1.z;
        acc[i][7] += av[i] * w1.w;
      }
    }
    __syncthreads();
  }
  const float4 bv = ((const float4*)b_l)[tx];
#pragma unroll
  for (int i = 0; i < 4; ++i) {
    const int n = nb + ty * 4 + i;
    if (n < N_NODES) {
      float4 gv, rv;
      gv.x = acc[i][0]; gv.y = acc[i][1]; gv.z = acc[i][2]; gv.w = acc[i][3];
      rv.x = acc[i][4] + bv.x; rv.y = acc[i][5] + bv.y;
      rv.z = acc[i][6] + bv.z; rv.w = acc[i][7] + bv.w;
      *(float4*)(g + (size_t)n * D + tx * 4) = gv;
      *(float4*)(r + (size_t)n * D + tx * 4) = rv;
    }
  }
}

// ---------------------------------------------------------------------------
// CSR build: degree histogram -> hierarchical exclusive scan -> slot scatter.
// ---------------------------------------------------------------------------
__global__ __launch_bounds__(256) void hist_kernel(const int* __restrict__ ei,
                                                   int* __restrict__ deg) {
  const int e = blockIdx.x * 256 + threadIdx.x;
  if (e < N_EDGES) atomicAdd(&deg[ei[N_EDGES + e]], 1);
}

// Stage 1: per-block (256-wide) exclusive scan + block totals.
__global__ __launch_bounds__(256) void scan1_kernel(
    const int* __restrict__ deg, int* __restrict__ offsets,
    int* __restrict__ partial) {
  __shared__ int sm[256];
  const int t = threadIdx.x;
  const int i = blockIdx.x * 256 + t;
  const int v = (i < N_NODES) ? deg[i] : 0;
  sm[t] = v;
  __syncthreads();
#pragma unroll
  for (int ofs = 1; ofs < 256; ofs <<= 1) {
    int x = sm[t];
    if (t >= ofs) x += sm[t - ofs];
    __syncthreads();
    sm[t] = x;
    __syncthreads();
  }
  if (i < N_NODES) offsets[i] = sm[t] - v;  // exclusive within block
  if (t == 255) partial[blockIdx.x] = sm[255];
}

// Stage 2: exclusive scan of the 196 block totals (in place).
__global__ __launch_bounds__(256) void scan2_kernel(int* __restrict__ partial) {
  __shared__ int sm[256];
  const int t = threadIdx.x;
  const int v = (t < NB_SCAN) ? partial[t] : 0;
  sm[t] = v;
  __syncthreads();
#pragma unroll
  for (int ofs = 1; ofs < 256; ofs <<= 1) {
    int x = sm[t];
    if (t >= ofs) x += sm[t - ofs];
    __syncthreads();
    sm[t] = x;
    __syncthreads();
  }
  if (t < NB_SCAN) partial[t] = sm[t] - v;  // exclusive
}

// Stage 3: add block base; emit offsets + cursor copy.
__global__ __launch_bounds__(256) void scan3_kernel(
    int* __restrict__ offsets, int* __restrict__ cursor,
    const int* __restrict__ partial) {
  const int i = blockIdx.x * 256 + threadIdx.x;
  if (i < N_NODES) {
    const int o = offsets[i] + partial[blockIdx.x];
    offsets[i] = o;
    cursor[i] = o;
  }
  if (i == 0) offsets[N_NODES] = N_EDGES;
}

__global__ __launch_bounds__(256) void scatter_kernel(
    const int* __restrict__ ei, int* __restrict__ cursor,
    int* __restrict__ csr) {
  const int e = blockIdx.x * 256 + threadIdx.x;
  if (e < N_EDGES) {
    const int src = ei[e];
    const int dst = ei[N_EDGES + e];
    const int pos = atomicAdd(&cursor[dst], 1);
    csr[pos] = src;
  }
}

// ---------------------------------------------------------------------------
// Mean-aggregate g rows per dst node (one wave per node), fuse + r -> out.
// ---------------------------------------------------------------------------
__global__ __launch_bounds__(256) void agg_kernel(
    const int* __restrict__ offsets, const int* __restrict__ csr,
    const float* __restrict__ g, const float* __restrict__ r,
    float* __restrict__ out) {
  const int l = threadIdx.x & 63;
  const int n = blockIdx.x * 4 + (threadIdx.x >> 6);
  const int s = offsets[n];
  const int e = offsets[n + 1];
  float2 acc = make_float2(0.0f, 0.0f);
  const float2* g2 = (const float2*)g;
  for (int base = s; base < e; base += 64) {
    const int rem = e - base;
    int idx = 0;
    if (l < rem) idx = csr[base + l];
    const int cnt = rem < 64 ? rem : 64;
    for (int j = 0; j < cnt; ++j) {
      const int src = __shfl(idx, j);
      const float2 v = g2[(size_t)src * 64 + l];
      acc.x += v.x;
      acc.y += v.y;
    }
  }
  const float inv = 1.0f / fmaxf((float)(e - s), 1.0f);
  const float2 rv = ((const float2*)r)[(size_t)n * 64 + l];
  float2 o;
  o.x = fmaf(acc.x, inv, rv.x);
  o.y = fmaf(acc.y, inv, rv.y);
  ((float2*)out)[(size_t)n * 64 + l] = o;
}

// ---------------------------------------------------------------------------
extern "C" void kernel_launch(void* const* d_in, const int* in_sizes, int n_in,
                              void* d_out, int out_size, void* d_ws,
                              size_t ws_size, hipStream_t stream) {
  const float* x = (const float*)d_in[0];
  const int* ei = (const int*)d_in[1];  // [2,E] flat: src [0,E), dst [E,2E)
  const float* mask = (const float*)d_in[2];
  const float* gamma = (const float*)d_in[3];
  const float* beta = (const float*)d_in[4];
  const float* w_l = (const float*)d_in[5];
  const float* b_l = (const float*)d_in[6];
  const float* w_r = (const float*)d_in[7];
  float* out = (float*)d_out;

  char* ws = (char*)d_ws;
  size_t off = 0;
  auto alloc = [&](size_t bytes) {
    char* p = ws + off;
    off += (bytes + 255) & ~(size_t)255;
    return p;
  };
  float* h = (float*)alloc((size_t)N_NODES * D * sizeof(float));
  float* g = (float*)alloc((size_t)N_NODES * D * sizeof(float));
  float* r = (float*)alloc((size_t)N_NODES * D * sizeof(float));
  float* wt = (float*)alloc((size_t)2 * D * D * sizeof(float));
  int* deg = (int*)alloc((size_t)N_NODES * sizeof(int));
  int* offsets = (int*)alloc((size_t)(N_NODES + 1) * sizeof(int));
  int* cursor = (int*)alloc((size_t)N_NODES * sizeof(int));
  int* partial = (int*)alloc((size_t)NB_SCAN * sizeof(int));
  int* csr = (int*)alloc((size_t)N_EDGES * sizeof(int));

  hipMemsetAsync(deg, 0, (size_t)N_NODES * sizeof(int), stream);
  wt_kernel<<<(2 * D * D) / 256, 256, 0, stream>>>(w_l, w_r, wt);
  ln_kernel<<<N_NODES / 4, 256, 0, stream>>>(x, mask, gamma, beta, h);
  gemm_kernel<<<(N_NODES + 31) / 32, 256, 0, stream>>>(h, wt, b_l, g, r);
  hist_kernel<<<N_EDGES / 256, 256, 0, stream>>>(ei, deg);
  scan1_kernel<<<NB_SCAN, 256, 0, stream>>>(deg, offsets, partial);
  scan2_kernel<<<1, 256, 0, stream>>>(partial);
  scan3_kernel<<<NB_SCAN, 256, 0, stream>>>(offsets, cursor, partial);
  scatter_kernel<<<N_EDGES / 256, 256, 0, stream>>>(ei, cursor, csr);
  agg_kernel<<<N_NODES / 4, 256, 0, stream>>>(offsets, csr, g, r, out);
}

// Round 3
// 278.059 us; speedup vs baseline: 1.4944x; 1.1523x over previous
//
#include <hip/hip_runtime.h>

#define N_NODES 50000
#define N_EDGES 800000
#define D 128
#define NB_SCAN ((N_NODES + 255) / 256)  // 196

// ---------------------------------------------------------------------------
// LayerNorm + ReLU + dropout-mask.  One wave (64 lanes) per node, float2/lane.
// ---------------------------------------------------------------------------
__global__ __launch_bounds__(256) void ln_kernel(
    const float* __restrict__ x, const float* __restrict__ mask,
    const float* __restrict__ gamma, const float* __restrict__ beta,
    float* __restrict__ h) {
  const int l = threadIdx.x & 63;
  const int n = blockIdx.x * 4 + (threadIdx.x >> 6);
  const float2 xv = ((const float2*)x)[(size_t)n * 64 + l];
  float s = xv.x + xv.y;
  float q = xv.x * xv.x + xv.y * xv.y;
#pragma unroll
  for (int m = 1; m < 64; m <<= 1) {
    s += __shfl_xor(s, m);
    q += __shfl_xor(q, m);
  }
  const float mean = s * (1.0f / 128.0f);
  const float var = q * (1.0f / 128.0f) - mean * mean;
  const float rs = rsqrtf(var + 1e-5f);
  const float2 gv = ((const float2*)gamma)[l];
  const float2 bv = ((const float2*)beta)[l];
  const float2 mv = ((const float2*)mask)[(size_t)n * 64 + l];
  float2 hv;
  hv.x = fmaxf((xv.x - mean) * rs * gv.x + bv.x, 0.0f) * mv.x;
  hv.y = fmaxf((xv.y - mean) * rs * gv.y + bv.y, 0.0f) * mv.y;
  ((float2*)h)[(size_t)n * 64 + l] = hv;
}

// ---------------------------------------------------------------------------
// Transpose/stack weights: wt[k][d] with d<128 -> w_l[d][k], d>=128 -> w_r.
// ---------------------------------------------------------------------------
__global__ __launch_bounds__(256) void wt_kernel(
    const float* __restrict__ w_l, const float* __restrict__ w_r,
    float* __restrict__ wt) {
  const int i = blockIdx.x * 256 + threadIdx.x;  // 128*256 total
  const int k = i >> 8;
  const int d = i & 255;
  wt[i] = (d < D) ? w_l[d * D + k] : w_r[(d - D) * D + k];
}

// ---------------------------------------------------------------------------
// Fused GEMM: g = h @ w_l^T, r = h @ w_r^T + b_l.
// Tile: 32 nodes x 256 outs per 256-thread block; K=128 in chunks of 32.
// ---------------------------------------------------------------------------
__global__ __launch_bounds__(256) void gemm_kernel(
    const float* __restrict__ h, const float* __restrict__ wt,
    const float* __restrict__ b_l, float* __restrict__ g,
    float* __restrict__ r) {
  __shared__ __align__(16) float As[32][32];    // [kk][node]
  __shared__ __align__(16) float Ws[32 * 256];  // [kk][d]
  const int t = threadIdx.x;
  const int tx = t & 31;
  const int ty = t >> 5;
  const int nb = blockIdx.x * 32;
  float acc[4][8];
#pragma unroll
  for (int i = 0; i < 4; ++i)
#pragma unroll
    for (int j = 0; j < 8; ++j) acc[i][j] = 0.0f;

  for (int c = 0; c < 4; ++c) {
    const int k0 = c * 32;
    {
      const int node = t >> 3;
      const int kk = (t & 7) * 4;
      int n = nb + node;
      if (n >= N_NODES) n = N_NODES - 1;  // clamp; store is guarded later
      const float4 v = *(const float4*)(h + (size_t)n * D + k0 + kk);
      As[kk + 0][node] = v.x;
      As[kk + 1][node] = v.y;
      As[kk + 2][node] = v.z;
      As[kk + 3][node] = v.w;
    }
    {
      const float4* src = (const float4*)(wt + (size_t)k0 * 256);
      float4* dstp = (float4*)(&Ws[0]);
#pragma unroll
      for (int i = 0; i < 8; ++i) dstp[t + 256 * i] = src[t + 256 * i];
    }
    __syncthreads();
#pragma unroll
    for (int kk = 0; kk < 32; ++kk) {
      const float4 a = *(const float4*)(&As[kk][ty * 4]);
      const float4 w0 = *(const float4*)(&Ws[kk * 256 + tx * 4]);
      const float4 w1 = *(const float4*)(&Ws[kk * 256 + 128 + tx * 4]);
      const float av[4] = {a.x, a.y, a.z, a.w};
#pragma unroll
      for (int i = 0; i < 4; ++i) {
        acc[i][0] += av[i] * w0.x;
        acc[i][1] += av[i] * w0.y;
        acc[i][2] += av[i] * w0.z;
        acc[i][3] += av[i] * w0.w;
        acc[i][4] += av[i] * w1.x;
        acc[i][5] += av[i] * w1.y;
        acc[i][6] += av[i] * w1.z;
        acc[i][7] += av[i] * w1.w;
      }
    }
    __syncthreads();
  }
  const float4 bv = ((const float4*)b_l)[tx];
#pragma unroll
  for (int i = 0; i < 4; ++i) {
    const int n = nb + ty * 4 + i;
    if (n < N_NODES) {
      float4 gv, rv;
      gv.x = acc[i][0]; gv.y = acc[i][1]; gv.z = acc[i][2]; gv.w = acc[i][3];
      rv.x = acc[i][4] + bv.x; rv.y = acc[i][5] + bv.y;
      rv.z = acc[i][6] + bv.z; rv.w = acc[i][7] + bv.w;
      *(float4*)(g + (size_t)n * D + tx * 4) = gv;
      *(float4*)(r + (size_t)n * D + tx * 4) = rv;
    }
  }
}

// ---------------------------------------------------------------------------
// CSR build: degree histogram (capturing per-edge rank) -> hierarchical scan
// -> atomic-free slot scatter.
// ---------------------------------------------------------------------------
__global__ __launch_bounds__(256) void hist_kernel(const int* __restrict__ ei,
                                                   int* __restrict__ deg,
                                                   int* __restrict__ rank) {
  const int e = blockIdx.x * 256 + threadIdx.x;
  if (e < N_EDGES) rank[e] = atomicAdd(&deg[ei[N_EDGES + e]], 1);
}

// Stage 1: per-block (256-wide) exclusive scan + block totals.
__global__ __launch_bounds__(256) void scan1_kernel(
    const int* __restrict__ deg, int* __restrict__ offsets,
    int* __restrict__ partial) {
  __shared__ int sm[256];
  const int t = threadIdx.x;
  const int i = blockIdx.x * 256 + t;
  const int v = (i < N_NODES) ? deg[i] : 0;
  sm[t] = v;
  __syncthreads();
#pragma unroll
  for (int ofs = 1; ofs < 256; ofs <<= 1) {
    int x = sm[t];
    if (t >= ofs) x += sm[t - ofs];
    __syncthreads();
    sm[t] = x;
    __syncthreads();
  }
  if (i < N_NODES) offsets[i] = sm[t] - v;  // exclusive within block
  if (t == 255) partial[blockIdx.x] = sm[255];
}

// Stage 2: exclusive scan of the 196 block totals (in place).
__global__ __launch_bounds__(256) void scan2_kernel(int* __restrict__ partial) {
  __shared__ int sm[256];
  const int t = threadIdx.x;
  const int v = (t < NB_SCAN) ? partial[t] : 0;
  sm[t] = v;
  __syncthreads();
#pragma unroll
  for (int ofs = 1; ofs < 256; ofs <<= 1) {
    int x = sm[t];
    if (t >= ofs) x += sm[t - ofs];
    __syncthreads();
    sm[t] = x;
    __syncthreads();
  }
  if (t < NB_SCAN) partial[t] = sm[t] - v;  // exclusive
}

// Stage 3: add block base; emit final offsets.
__global__ __launch_bounds__(256) void scan3_kernel(
    int* __restrict__ offsets, const int* __restrict__ partial) {
  const int i = blockIdx.x * 256 + threadIdx.x;
  if (i < N_NODES) offsets[i] += partial[blockIdx.x];
  if (i == 0) offsets[N_NODES] = N_EDGES;
}

__global__ __launch_bounds__(256) void scatter_kernel(
    const int* __restrict__ ei, const int* __restrict__ offsets,
    const int* __restrict__ rank, int* __restrict__ csr) {
  const int e = blockIdx.x * 256 + threadIdx.x;
  if (e < N_EDGES) {
    const int dst = ei[N_EDGES + e];
    csr[offsets[dst] + rank[e]] = ei[e];
  }
}

// ---------------------------------------------------------------------------
// Mean-aggregate g rows per dst node, fuse + r -> out.
// One wave per node; 2 rows per vmem instruction (half-wave x float4 = 1KB),
// 8 rows per unrolled step (4 independent loads in flight).
// ---------------------------------------------------------------------------
__global__ __launch_bounds__(256) void agg_kernel(
    const int* __restrict__ offsets, const int* __restrict__ csr,
    const float* __restrict__ g, const float* __restrict__ r,
    float* __restrict__ out) {
  const int l = threadIdx.x & 63;
  const int half = l >> 5;  // 0: even row of pair, 1: odd row
  const int c = l & 31;     // float4 column group within the 128-float row
  const int n = blockIdx.x * 4 + (threadIdx.x >> 6);
  const int s = offsets[n];
  const int e = offsets[n + 1];
  const float4* g4 = (const float4*)g;
  float4 a0 = {0, 0, 0, 0}, a1 = {0, 0, 0, 0};
  float4 a2 = {0, 0, 0, 0}, a3 = {0, 0, 0, 0};
  for (int base = s; base < e; base += 64) {
    const int cnt = min(e - base, 64);
    int idx = (l < cnt) ? csr[base + l] : 0;
    int j = 0;
    for (; j + 8 <= cnt; j += 8) {
      const int i0 = __shfl(idx, j + 0 + half);
      const int i1 = __shfl(idx, j + 2 + half);
      const int i2 = __shfl(idx, j + 4 + half);
      const int i3 = __shfl(idx, j + 6 + half);
      const float4 v0 = g4[(size_t)i0 * 32 + c];
      const float4 v1 = g4[(size_t)i1 * 32 + c];
      const float4 v2 = g4[(size_t)i2 * 32 + c];
      const float4 v3 = g4[(size_t)i3 * 32 + c];
      a0.x += v0.x; a0.y += v0.y; a0.z += v0.z; a0.w += v0.w;
      a1.x += v1.x; a1.y += v1.y; a1.z += v1.z; a1.w += v1.w;
      a2.x += v2.x; a2.y += v2.y; a2.z += v2.z; a2.w += v2.w;
      a3.x += v3.x; a3.y += v3.y; a3.z += v3.z; a3.w += v3.w;
    }
    for (; j + 2 <= cnt; j += 2) {
      const int i0 = __shfl(idx, j + half);
      const float4 v0 = g4[(size_t)i0 * 32 + c];
      a0.x += v0.x; a0.y += v0.y; a0.z += v0.z; a0.w += v0.w;
    }
    if (j < cnt) {  // odd leftover row: low half only
      const int i0 = __shfl(idx, j);
      if (half == 0) {
        const float4 v0 = g4[(size_t)i0 * 32 + c];
        a0.x += v0.x; a0.y += v0.y; a0.z += v0.z; a0.w += v0.w;
      }
    }
  }
  float4 acc;
  acc.x = (a0.x + a1.x) + (a2.x + a3.x);
  acc.y = (a0.y + a1.y) + (a2.y + a3.y);
  acc.z = (a0.z + a1.z) + (a2.z + a3.z);
  acc.w = (a0.w + a1.w) + (a2.w + a3.w);
  // combine the two half-wave partial sums (row parity split)
  acc.x += __shfl_xor(acc.x, 32);
  acc.y += __shfl_xor(acc.y, 32);
  acc.z += __shfl_xor(acc.z, 32);
  acc.w += __shfl_xor(acc.w, 32);
  if (half == 0) {
    const float inv = 1.0f / fmaxf((float)(e - s), 1.0f);
    const float4 rv = ((const float4*)r)[(size_t)n * 32 + c];
    float4 o;
    o.x = fmaf(acc.x, inv, rv.x);
    o.y = fmaf(acc.y, inv, rv.y);
    o.z = fmaf(acc.z, inv, rv.z);
    o.w = fmaf(acc.w, inv, rv.w);
    ((float4*)out)[(size_t)n * 32 + c] = o;
  }
}

// ---------------------------------------------------------------------------
extern "C" void kernel_launch(void* const* d_in, const int* in_sizes, int n_in,
                              void* d_out, int out_size, void* d_ws,
                              size_t ws_size, hipStream_t stream) {
  const float* x = (const float*)d_in[0];
  const int* ei = (const int*)d_in[1];  // [2,E] flat: src [0,E), dst [E,2E)
  const float* mask = (const float*)d_in[2];
  const float* gamma = (const float*)d_in[3];
  const float* beta = (const float*)d_in[4];
  const float* w_l = (const float*)d_in[5];
  const float* b_l = (const float*)d_in[6];
  const float* w_r = (const float*)d_in[7];
  float* out = (float*)d_out;

  char* ws = (char*)d_ws;
  size_t off = 0;
  auto alloc = [&](size_t bytes) {
    char* p = ws + off;
    off += (bytes + 255) & ~(size_t)255;
    return p;
  };
  float* h = (float*)alloc((size_t)N_NODES * D * sizeof(float));
  float* g = (float*)alloc((size_t)N_NODES * D * sizeof(float));
  float* r = (float*)alloc((size_t)N_NODES * D * sizeof(float));
  float* wt = (float*)alloc((size_t)2 * D * D * sizeof(float));
  int* deg = (int*)alloc((size_t)N_NODES * sizeof(int));
  int* offsets = (int*)alloc((size_t)(N_NODES + 1) * sizeof(int));
  int* partial = (int*)alloc((size_t)NB_SCAN * sizeof(int));
  int* rank = (int*)alloc((size_t)N_EDGES * sizeof(int));
  int* csr = (int*)alloc((size_t)N_EDGES * sizeof(int));

  hipMemsetAsync(deg, 0, (size_t)N_NODES * sizeof(int), stream);
  wt_kernel<<<(2 * D * D) / 256, 256, 0, stream>>>(w_l, w_r, wt);
  ln_kernel<<<N_NODES / 4, 256, 0, stream>>>(x, mask, gamma, beta, h);
  gemm_kernel<<<(N_NODES + 31) / 32, 256, 0, stream>>>(h, wt, b_l, g, r);
  hist_kernel<<<N_EDGES / 256, 256, 0, stream>>>(ei, deg, rank);
  scan1_kernel<<<NB_SCAN, 256, 0, stream>>>(deg, offsets, partial);
  scan2_kernel<<<1, 256, 0, stream>>>(partial);
  scan3_kernel<<<NB_SCAN, 256, 0, stream>>>(offsets, partial);
  scatter_kernel<<<N_EDGES / 256, 256, 0, stream>>>(ei, offsets, rank, csr);
  agg_kernel<<<N_NODES / 4, 256, 0, stream>>>(offsets, csr, g, r, out);
}

// Round 4
// 255.296 us; speedup vs baseline: 1.6276x; 1.0892x over previous
//
#include <hip/hip_runtime.h>
#include <hip/hip_bf16.h>

#define N_NODES 50000
#define N_EDGES 800000
#define D 128
#define NB_SCAN ((N_NODES + 255) / 256)  // 196

__device__ __forceinline__ unsigned int bf16u(float f) {
  __hip_bfloat16 b = __float2bfloat16(f);
  return (unsigned int)*reinterpret_cast<unsigned short*>(&b);
}

// ---------------------------------------------------------------------------
// LayerNorm + ReLU + dropout-mask.  One wave (64 lanes) per node, float2/lane.
// ---------------------------------------------------------------------------
__global__ __launch_bounds__(256) void ln_kernel(
    const float* __restrict__ x, const float* __restrict__ mask,
    const float* __restrict__ gamma, const float* __restrict__ beta,
    float* __restrict__ h) {
  const int l = threadIdx.x & 63;
  const int n = blockIdx.x * 4 + (threadIdx.x >> 6);
  const float2 xv = ((const float2*)x)[(size_t)n * 64 + l];
  float s = xv.x + xv.y;
  float q = xv.x * xv.x + xv.y * xv.y;
#pragma unroll
  for (int m = 1; m < 64; m <<= 1) {
    s += __shfl_xor(s, m);
    q += __shfl_xor(q, m);
  }
  const float mean = s * (1.0f / 128.0f);
  const float var = q * (1.0f / 128.0f) - mean * mean;
  const float rs = rsqrtf(var + 1e-5f);
  const float2 gv = ((const float2*)gamma)[l];
  const float2 bv = ((const float2*)beta)[l];
  const float2 mv = ((const float2*)mask)[(size_t)n * 64 + l];
  float2 hv;
  hv.x = fmaxf((xv.x - mean) * rs * gv.x + bv.x, 0.0f) * mv.x;
  hv.y = fmaxf((xv.y - mean) * rs * gv.y + bv.y, 0.0f) * mv.y;
  ((float2*)h)[(size_t)n * 64 + l] = hv;
}

// ---------------------------------------------------------------------------
// Transpose/stack weights: wt[k][d] with d<128 -> w_l[d][k], d>=128 -> w_r.
// ---------------------------------------------------------------------------
__global__ __launch_bounds__(256) void wt_kernel(
    const float* __restrict__ w_l, const float* __restrict__ w_r,
    float* __restrict__ wt) {
  const int i = blockIdx.x * 256 + threadIdx.x;  // 128*256 total
  const int k = i >> 8;
  const int d = i & 255;
  wt[i] = (d < D) ? w_l[d * D + k] : w_r[(d - D) * D + k];
}

// ---------------------------------------------------------------------------
// Fused GEMM: g = bf16(h @ w_l^T), r = h @ w_r^T + b_l (fp32).
// Tile: 32 nodes x 256 outs per 256-thread block; K=128 in chunks of 32.
// ---------------------------------------------------------------------------
__global__ __launch_bounds__(256) void gemm_kernel(
    const float* __restrict__ h, const float* __restrict__ wt,
    const float* __restrict__ b_l, unsigned int* __restrict__ gb,
    float* __restrict__ r) {
  __shared__ __align__(16) float As[32][32];    // [kk][node]
  __shared__ __align__(16) float Ws[32 * 256];  // [kk][d]
  const int t = threadIdx.x;
  const int tx = t & 31;
  const int ty = t >> 5;
  const int nb = blockIdx.x * 32;
  float acc[4][8];
#pragma unroll
  for (int i = 0; i < 4; ++i)
#pragma unroll
    for (int j = 0; j < 8; ++j) acc[i][j] = 0.0f;

  for (int c = 0; c < 4; ++c) {
    const int k0 = c * 32;
    {
      const int node = t >> 3;
      const int kk = (t & 7) * 4;
      int n = nb + node;
      if (n >= N_NODES) n = N_NODES - 1;  // clamp; store is guarded later
      const float4 v = *(const float4*)(h + (size_t)n * D + k0 + kk);
      As[kk + 0][node] = v.x;
      As[kk + 1][node] = v.y;
      As[kk + 2][node] = v.z;
      As[kk + 3][node] = v.w;
    }
    {
      const float4* src = (const float4*)(wt + (size_t)k0 * 256);
      float4* dstp = (float4*)(&Ws[0]);
#pragma unroll
      for (int i = 0; i < 8; ++i) dstp[t + 256 * i] = src[t + 256 * i];
    }
    __syncthreads();
#pragma unroll
    for (int kk = 0; kk < 32; ++kk) {
      const float4 a = *(const float4*)(&As[kk][ty * 4]);
      const float4 w0 = *(const float4*)(&Ws[kk * 256 + tx * 4]);
      const float4 w1 = *(const float4*)(&Ws[kk * 256 + 128 + tx * 4]);
      const float av[4] = {a.x, a.y, a.z, a.w};
#pragma unroll
      for (int i = 0; i < 4; ++i) {
        acc[i][0] += av[i] * w0.x;
        acc[i][1] += av[i] * w0.y;
        acc[i][2] += av[i] * w0.z;
        acc[i][3] += av[i] * w0.w;
        acc[i][4] += av[i] * w1.x;
        acc[i][5] += av[i] * w1.y;
        acc[i][6] += av[i] * w1.z;
        acc[i][7] += av[i] * w1.w;
      }
    }
    __syncthreads();
  }
  const float4 bv = ((const float4*)b_l)[tx];
#pragma unroll
  for (int i = 0; i < 4; ++i) {
    const int n = nb + ty * 4 + i;
    if (n < N_NODES) {
      // g row: 128 bf16 = 32 uint2 per row; thread writes cols tx*4..tx*4+3
      uint2 gp;
      gp.x = (bf16u(acc[i][1]) << 16) | bf16u(acc[i][0]);
      gp.y = (bf16u(acc[i][3]) << 16) | bf16u(acc[i][2]);
      ((uint2*)gb)[(size_t)n * 32 + tx] = gp;
      float4 rv;
      rv.x = acc[i][4] + bv.x; rv.y = acc[i][5] + bv.y;
      rv.z = acc[i][6] + bv.z; rv.w = acc[i][7] + bv.w;
      *(float4*)(r + (size_t)n * D + tx * 4) = rv;
    }
  }
}

// ---------------------------------------------------------------------------
// CSR build: degree histogram (capturing per-edge rank) -> hierarchical scan
// -> atomic-free slot scatter.
// ---------------------------------------------------------------------------
__global__ __launch_bounds__(256) void hist_kernel(const int* __restrict__ ei,
                                                   int* __restrict__ deg,
                                                   int* __restrict__ rank) {
  const int e = blockIdx.x * 256 + threadIdx.x;
  if (e < N_EDGES) rank[e] = atomicAdd(&deg[ei[N_EDGES + e]], 1);
}

__global__ __launch_bounds__(256) void scan1_kernel(
    const int* __restrict__ deg, int* __restrict__ offsets,
    int* __restrict__ partial) {
  __shared__ int sm[256];
  const int t = threadIdx.x;
  const int i = blockIdx.x * 256 + t;
  const int v = (i < N_NODES) ? deg[i] : 0;
  sm[t] = v;
  __syncthreads();
#pragma unroll
  for (int ofs = 1; ofs < 256; ofs <<= 1) {
    int x = sm[t];
    if (t >= ofs) x += sm[t - ofs];
    __syncthreads();
    sm[t] = x;
    __syncthreads();
  }
  if (i < N_NODES) offsets[i] = sm[t] - v;
  if (t == 255) partial[blockIdx.x] = sm[255];
}

__global__ __launch_bounds__(256) void scan2_kernel(int* __restrict__ partial) {
  __shared__ int sm[256];
  const int t = threadIdx.x;
  const int v = (t < NB_SCAN) ? partial[t] : 0;
  sm[t] = v;
  __syncthreads();
#pragma unroll
  for (int ofs = 1; ofs < 256; ofs <<= 1) {
    int x = sm[t];
    if (t >= ofs) x += sm[t - ofs];
    __syncthreads();
    sm[t] = x;
    __syncthreads();
  }
  if (t < NB_SCAN) partial[t] = sm[t] - v;
}

__global__ __launch_bounds__(256) void scan3_kernel(
    int* __restrict__ offsets, const int* __restrict__ partial) {
  const int i = blockIdx.x * 256 + threadIdx.x;
  if (i < N_NODES) offsets[i] += partial[blockIdx.x];
  if (i == 0) offsets[N_NODES] = N_EDGES;
}

__global__ __launch_bounds__(256) void scatter_kernel(
    const int* __restrict__ ei, const int* __restrict__ offsets,
    const int* __restrict__ rank, int* __restrict__ csr) {
  const int e = blockIdx.x * 256 + threadIdx.x;
  if (e < N_EDGES) {
    const int dst = ei[N_EDGES + e];
    csr[offsets[dst] + rank[e]] = ei[e];
  }
}

// ---------------------------------------------------------------------------
// Mean-aggregate bf16 g rows per dst node, fuse + r -> out (fp32).
// One wave per node; 4 rows per vmem instruction (quarter-wave x uint4 = 1KB),
// 16 rows per unrolled step (4 loads in flight). fp32 accumulate; quarters
// combined via shfl_xor(16|32).
// ---------------------------------------------------------------------------
#define ACC8(v)                                  \
  do {                                           \
    acc[0] += __uint_as_float((v).x << 16);      \
    acc[1] += __uint_as_float((v).x & 0xffff0000u); \
    acc[2] += __uint_as_float((v).y << 16);      \
    acc[3] += __uint_as_float((v).y & 0xffff0000u); \
    acc[4] += __uint_as_float((v).z << 16);      \
    acc[5] += __uint_as_float((v).z & 0xffff0000u); \
    acc[6] += __uint_as_float((v).w << 16);      \
    acc[7] += __uint_as_float((v).w & 0xffff0000u); \
  } while (0)

__global__ __launch_bounds__(256) void agg_kernel(
    const int* __restrict__ offsets, const int* __restrict__ csr,
    const unsigned int* __restrict__ gb, const float* __restrict__ r,
    float* __restrict__ out) {
  const int l = threadIdx.x & 63;
  const int q = l >> 4;  // row within group of 4
  const int c = l & 15;  // 16B chunk within the 256B bf16 row
  const int n = blockIdx.x * 4 + (threadIdx.x >> 6);
  const int s = offsets[n];
  const int e = offsets[n + 1];
  const uint4* g4 = (const uint4*)gb;
  float acc[8];
#pragma unroll
  for (int k = 0; k < 8; ++k) acc[k] = 0.0f;
  for (int base = s; base < e; base += 64) {
    const int cnt = min(e - base, 64);
    int idx = (l < cnt) ? csr[base + l] : 0;
    int j = 0;
    for (; j + 16 <= cnt; j += 16) {
      const int i0 = __shfl(idx, j + 0 + q);
      const int i1 = __shfl(idx, j + 4 + q);
      const int i2 = __shfl(idx, j + 8 + q);
      const int i3 = __shfl(idx, j + 12 + q);
      const uint4 v0 = g4[(size_t)i0 * 16 + c];
      const uint4 v1 = g4[(size_t)i1 * 16 + c];
      const uint4 v2 = g4[(size_t)i2 * 16 + c];
      const uint4 v3 = g4[(size_t)i3 * 16 + c];
      ACC8(v0);
      ACC8(v1);
      ACC8(v2);
      ACC8(v3);
    }
    for (; j + 4 <= cnt; j += 4) {
      const int i0 = __shfl(idx, j + q);
      const uint4 v0 = g4[(size_t)i0 * 16 + c];
      ACC8(v0);
    }
    if (j < cnt) {
      const int rem = cnt - j;  // 1..3 leftover rows
      const int i0 = __shfl(idx, j + min(q, rem - 1));
      if (q < rem) {
        const uint4 v0 = g4[(size_t)i0 * 16 + c];
        ACC8(v0);
      }
    }
  }
#pragma unroll
  for (int k = 0; k < 8; ++k) {
    acc[k] += __shfl_xor(acc[k], 16);
    acc[k] += __shfl_xor(acc[k], 32);
  }
  if (l < 16) {
    const float inv = 1.0f / fmaxf((float)(e - s), 1.0f);
    const float4 r0 = ((const float4*)r)[(size_t)n * 32 + c * 2 + 0];
    const float4 r1 = ((const float4*)r)[(size_t)n * 32 + c * 2 + 1];
    float4 o0, o1;
    o0.x = fmaf(acc[0], inv, r0.x);
    o0.y = fmaf(acc[1], inv, r0.y);
    o0.z = fmaf(acc[2], inv, r0.z);
    o0.w = fmaf(acc[3], inv, r0.w);
    o1.x = fmaf(acc[4], inv, r1.x);
    o1.y = fmaf(acc[5], inv, r1.y);
    o1.z = fmaf(acc[6], inv, r1.z);
    o1.w = fmaf(acc[7], inv, r1.w);
    ((float4*)out)[(size_t)n * 32 + c * 2 + 0] = o0;
    ((float4*)out)[(size_t)n * 32 + c * 2 + 1] = o1;
  }
}

// ---------------------------------------------------------------------------
extern "C" void kernel_launch(void* const* d_in, const int* in_sizes, int n_in,
                              void* d_out, int out_size, void* d_ws,
                              size_t ws_size, hipStream_t stream) {
  const float* x = (const float*)d_in[0];
  const int* ei = (const int*)d_in[1];  // [2,E] flat: src [0,E), dst [E,2E)
  const float* mask = (const float*)d_in[2];
  const float* gamma = (const float*)d_in[3];
  const float* beta = (const float*)d_in[4];
  const float* w_l = (const float*)d_in[5];
  const float* b_l = (const float*)d_in[6];
  const float* w_r = (const float*)d_in[7];
  float* out = (float*)d_out;

  char* ws = (char*)d_ws;
  size_t off = 0;
  auto alloc = [&](size_t bytes) {
    char* p = ws + off;
    off += (bytes + 255) & ~(size_t)255;
    return p;
  };
  float* h = (float*)alloc((size_t)N_NODES * D * sizeof(float));
  unsigned int* gb =
      (unsigned int*)alloc((size_t)N_NODES * D * sizeof(unsigned short));
  float* r = (float*)alloc((size_t)N_NODES * D * sizeof(float));
  float* wt = (float*)alloc((size_t)2 * D * D * sizeof(float));
  int* deg = (int*)alloc((size_t)N_NODES * sizeof(int));
  int* offsets = (int*)alloc((size_t)(N_NODES + 1) * sizeof(int));
  int* partial = (int*)alloc((size_t)NB_SCAN * sizeof(int));
  int* rank = (int*)alloc((size_t)N_EDGES * sizeof(int));
  int* csr = (int*)alloc((size_t)N_EDGES * sizeof(int));

  hipMemsetAsync(deg, 0, (size_t)N_NODES * sizeof(int), stream);
  wt_kernel<<<(2 * D * D) / 256, 256, 0, stream>>>(w_l, w_r, wt);
  ln_kernel<<<N_NODES / 4, 256, 0, stream>>>(x, mask, gamma, beta, h);
  gemm_kernel<<<(N_NODES + 31) / 32, 256, 0, stream>>>(h, wt, b_l, gb, r);
  hist_kernel<<<N_EDGES / 256, 256, 0, stream>>>(ei, deg, rank);
  scan1_kernel<<<NB_SCAN, 256, 0, stream>>>(deg, offsets, partial);
  scan2_kernel<<<1, 256, 0, stream>>>(partial);
  scan3_kernel<<<NB_SCAN, 256, 0, stream>>>(offsets, partial);
  scatter_kernel<<<N_EDGES / 256, 256, 0, stream>>>(ei, offsets, rank, csr);
  agg_kernel<<<N_NODES / 4, 256, 0, stream>>>(offsets, csr, gb, r, out);
}

// Round 5
// 240.263 us; speedup vs baseline: 1.7295x; 1.0626x over previous
//
#include <hip/hip_runtime.h>
#include <hip/hip_bf16.h>

#define N_NODES 50000
#define N_EDGES 800000
#define D 128
#define NB_SCAN ((N_NODES + 255) / 256)  // 196

typedef short bf16x8 __attribute__((ext_vector_type(8)));
typedef float f32x4 __attribute__((ext_vector_type(4)));

__device__ __forceinline__ unsigned int bf16u(float f) {
  __hip_bfloat16 b = __float2bfloat16(f);
  return (unsigned int)*reinterpret_cast<unsigned short*>(&b);
}

// ---------------------------------------------------------------------------
// LayerNorm + ReLU + dropout-mask -> bf16 h.  One wave per node, float2/lane.
// ---------------------------------------------------------------------------
__global__ __launch_bounds__(256) void ln_kernel(
    const float* __restrict__ x, const float* __restrict__ mask,
    const float* __restrict__ gamma, const float* __restrict__ beta,
    unsigned int* __restrict__ hb) {
  const int l = threadIdx.x & 63;
  const int n = blockIdx.x * 4 + (threadIdx.x >> 6);
  const float2 xv = ((const float2*)x)[(size_t)n * 64 + l];
  float s = xv.x + xv.y;
  float q = xv.x * xv.x + xv.y * xv.y;
#pragma unroll
  for (int m = 1; m < 64; m <<= 1) {
    s += __shfl_xor(s, m);
    q += __shfl_xor(q, m);
  }
  const float mean = s * (1.0f / 128.0f);
  const float var = q * (1.0f / 128.0f) - mean * mean;
  const float rs = rsqrtf(var + 1e-5f);
  const float2 gv = ((const float2*)gamma)[l];
  const float2 bv = ((const float2*)beta)[l];
  const float2 mv = ((const float2*)mask)[(size_t)n * 64 + l];
  const float h0 = fmaxf((xv.x - mean) * rs * gv.x + bv.x, 0.0f) * mv.x;
  const float h1 = fmaxf((xv.y - mean) * rs * gv.y + bv.y, 0.0f) * mv.y;
  hb[(size_t)n * 64 + l] = (bf16u(h1) << 16) | bf16u(h0);
}

// ---------------------------------------------------------------------------
// Cast stacked weights to bf16 row-major [256][128]: rows 0..127 = w_l,
// rows 128..255 = w_r.  (B-fragment reads contiguous along k.)
// ---------------------------------------------------------------------------
__global__ __launch_bounds__(256) void wt_kernel(
    const float* __restrict__ w_l, const float* __restrict__ w_r,
    unsigned int* __restrict__ wtb) {
  const int i = blockIdx.x * 256 + threadIdx.x;  // 0..16383 (uint = 2 bf16)
  const float* src = (i < 8192) ? w_l : w_r;
  const int j = (i < 8192) ? 2 * i : 2 * (i - 8192);
  wtb[i] = (bf16u(src[j + 1]) << 16) | bf16u(src[j]);
}

// ---------------------------------------------------------------------------
// MFMA GEMM: [g | r] = h_bf16 @ [w_l | w_r]^T_bf16  (+ b_l on the r half).
// Block = 4 waves = 64 nodes x 64 outs; grid (782, 4); by<2 -> g, by>=2 -> r.
// Wave: 16 nodes x 64 outs = 4 x mfma_f32_16x16x32_bf16 over K=128 (4 chunks).
// A/B fragments load directly from global (no LDS in main loop); LDS only for
// the epilogue transpose.
// A[m=lane&15][k=quad*8+j]; B[k=quad*8+j][n=lane&15]; D[m=quad*4+reg][n=lane&15].
// ---------------------------------------------------------------------------
__global__ __launch_bounds__(256) void gemm_kernel(
    const unsigned short* __restrict__ hb, const unsigned short* __restrict__ wtb,
    const float* __restrict__ b_l, unsigned int* __restrict__ gb,
    float* __restrict__ r) {
  __shared__ float lds[64][65];
  const int t = threadIdx.x;
  const int w = t >> 6;    // wave 0..3
  const int l = t & 63;    // lane
  const int lm = l & 15;   // m (A) / n (B,D) index
  const int quad = l >> 4; // k-group / D-row group
  const int nb = blockIdx.x * 64;
  const int by = blockIdx.y;  // 0..3: out cols [by*64, by*64+64)

  // A fragments: node = nb + w*16 + lm, k = ch*32 + quad*8 (+0..7)
  int anode = nb + w * 16 + lm;
  if (anode >= N_NODES) anode = N_NODES - 1;
  const unsigned short* arow = hb + (size_t)anode * D + quad * 8;
  bf16x8 af[4];
#pragma unroll
  for (int ch = 0; ch < 4; ++ch)
    af[ch] = *(const bf16x8*)(arow + ch * 32);

  // B fragments: out-row d = by*64 + sub*16 + lm, k = ch*32 + quad*8
  const unsigned short* brow = wtb + (size_t)(by * 64 + lm) * D + quad * 8;
  bf16x8 bf[4][4];
#pragma unroll
  for (int sub = 0; sub < 4; ++sub)
#pragma unroll
    for (int ch = 0; ch < 4; ++ch)
      bf[sub][ch] = *(const bf16x8*)(brow + sub * 16 * D + ch * 32);

  f32x4 acc[4];
#pragma unroll
  for (int sub = 0; sub < 4; ++sub) acc[sub] = (f32x4){0.f, 0.f, 0.f, 0.f};
#pragma unroll
  for (int ch = 0; ch < 4; ++ch)
#pragma unroll
    for (int sub = 0; sub < 4; ++sub)
      acc[sub] = __builtin_amdgcn_mfma_f32_16x16x32_bf16(af[ch], bf[sub][ch],
                                                         acc[sub], 0, 0, 0);

  // Transpose through LDS: row = local node, col = local out.
#pragma unroll
  for (int sub = 0; sub < 4; ++sub)
#pragma unroll
    for (int reg = 0; reg < 4; ++reg)
      lds[w * 16 + quad * 4 + reg][sub * 16 + lm] = acc[sub][reg];
  __syncthreads();

  if (by < 2) {
    // g half: pack bf16, 8 cols (one uint4) per thread, 2 rows per thread.
#pragma unroll
    for (int i = 0; i < 2; ++i) {
      const int row = (t >> 3) + i * 32;
      const int grp = t & 7;
      const int node = nb + row;
      if (node < N_NODES) {
        const float* lr = &lds[row][grp * 8];
        uint4 p;
        p.x = (bf16u(lr[1]) << 16) | bf16u(lr[0]);
        p.y = (bf16u(lr[3]) << 16) | bf16u(lr[2]);
        p.z = (bf16u(lr[5]) << 16) | bf16u(lr[4]);
        p.w = (bf16u(lr[7]) << 16) | bf16u(lr[6]);
        ((uint4*)gb)[(size_t)node * 16 + by * 8 + grp] = p;
      }
    }
  } else {
    // r half: fp32 + bias, 16 cols per thread, one row per thread.
    const int row = t >> 2;
    const int grp = t & 3;
    const int node = nb + row;
    const int col0 = (by - 2) * 64 + grp * 16;  // col within r's 128
    if (node < N_NODES) {
#pragma unroll
      for (int qd = 0; qd < 4; ++qd) {
        const float4 bv = *(const float4*)(b_l + col0 + qd * 4);
        const float* lr = &lds[row][grp * 16 + qd * 4];
        float4 o;
        o.x = lr[0] + bv.x;
        o.y = lr[1] + bv.y;
        o.z = lr[2] + bv.z;
        o.w = lr[3] + bv.w;
        *(float4*)(r + (size_t)node * D + col0 + qd * 4) = o;
      }
    }
  }
}

// ---------------------------------------------------------------------------
// CSR build: degree histogram (capturing per-edge rank) -> hierarchical scan
// -> atomic-free slot scatter.
// ---------------------------------------------------------------------------
__global__ __launch_bounds__(256) void hist_kernel(const int* __restrict__ ei,
                                                   int* __restrict__ deg,
                                                   int* __restrict__ rank) {
  const int e = blockIdx.x * 256 + threadIdx.x;
  if (e < N_EDGES) rank[e] = atomicAdd(&deg[ei[N_EDGES + e]], 1);
}

__global__ __launch_bounds__(256) void scan1_kernel(
    const int* __restrict__ deg, int* __restrict__ offsets,
    int* __restrict__ partial) {
  __shared__ int sm[256];
  const int t = threadIdx.x;
  const int i = blockIdx.x * 256 + t;
  const int v = (i < N_NODES) ? deg[i] : 0;
  sm[t] = v;
  __syncthreads();
#pragma unroll
  for (int ofs = 1; ofs < 256; ofs <<= 1) {
    int x = sm[t];
    if (t >= ofs) x += sm[t - ofs];
    __syncthreads();
    sm[t] = x;
    __syncthreads();
  }
  if (i < N_NODES) offsets[i] = sm[t] - v;
  if (t == 255) partial[blockIdx.x] = sm[255];
}

__global__ __launch_bounds__(256) void scan2_kernel(int* __restrict__ partial) {
  __shared__ int sm[256];
  const int t = threadIdx.x;
  const int v = (t < NB_SCAN) ? partial[t] : 0;
  sm[t] = v;
  __syncthreads();
#pragma unroll
  for (int ofs = 1; ofs < 256; ofs <<= 1) {
    int x = sm[t];
    if (t >= ofs) x += sm[t - ofs];
    __syncthreads();
    sm[t] = x;
    __syncthreads();
  }
  if (t < NB_SCAN) partial[t] = sm[t] - v;
}

__global__ __launch_bounds__(256) void scan3_kernel(
    int* __restrict__ offsets, const int* __restrict__ partial) {
  const int i = blockIdx.x * 256 + threadIdx.x;
  if (i < N_NODES) offsets[i] += partial[blockIdx.x];
  if (i == 0) offsets[N_NODES] = N_EDGES;
}

__global__ __launch_bounds__(256) void scatter_kernel(
    const int* __restrict__ ei, const int* __restrict__ offsets,
    const int* __restrict__ rank, int* __restrict__ csr) {
  const int e = blockIdx.x * 256 + threadIdx.x;
  if (e < N_EDGES) {
    const int dst = ei[N_EDGES + e];
    csr[offsets[dst] + rank[e]] = ei[e];
  }
}

// ---------------------------------------------------------------------------
// Mean-aggregate bf16 g rows per dst node, fuse + r -> out (fp32).
// One wave per node; 4 rows per vmem instruction (quarter-wave x uint4 = 1KB),
// 16 rows per unrolled step. fp32 accumulate; quarters via shfl_xor(16|32).
// ---------------------------------------------------------------------------
#define ACC8(v)                                     \
  do {                                              \
    acc[0] += __uint_as_float((v).x << 16);         \
    acc[1] += __uint_as_float((v).x & 0xffff0000u); \
    acc[2] += __uint_as_float((v).y << 16);         \
    acc[3] += __uint_as_float((v).y & 0xffff0000u); \
    acc[4] += __uint_as_float((v).z << 16);         \
    acc[5] += __uint_as_float((v).z & 0xffff0000u); \
    acc[6] += __uint_as_float((v).w << 16);         \
    acc[7] += __uint_as_float((v).w & 0xffff0000u); \
  } while (0)

__global__ __launch_bounds__(256) void agg_kernel(
    const int* __restrict__ offsets, const int* __restrict__ csr,
    const unsigned int* __restrict__ gb, const float* __restrict__ r,
    float* __restrict__ out) {
  const int l = threadIdx.x & 63;
  const int q = l >> 4;  // row within group of 4
  const int c = l & 15;  // 16B chunk within the 256B bf16 row
  const int n = blockIdx.x * 4 + (threadIdx.x >> 6);
  const int s = offsets[n];
  const int e = offsets[n + 1];
  const uint4* g4 = (const uint4*)gb;
  float acc[8];
#pragma unroll
  for (int k = 0; k < 8; ++k) acc[k] = 0.0f;
  for (int base = s; base < e; base += 64) {
    const int cnt = min(e - base, 64);
    int idx = (l < cnt) ? csr[base + l] : 0;
    int j = 0;
    for (; j + 16 <= cnt; j += 16) {
      const int i0 = __shfl(idx, j + 0 + q);
      const int i1 = __shfl(idx, j + 4 + q);
      const int i2 = __shfl(idx, j + 8 + q);
      const int i3 = __shfl(idx, j + 12 + q);
      const uint4 v0 = g4[(size_t)i0 * 16 + c];
      const uint4 v1 = g4[(size_t)i1 * 16 + c];
      const uint4 v2 = g4[(size_t)i2 * 16 + c];
      const uint4 v3 = g4[(size_t)i3 * 16 + c];
      ACC8(v0);
      ACC8(v1);
      ACC8(v2);
      ACC8(v3);
    }
    for (; j + 4 <= cnt; j += 4) {
      const int i0 = __shfl(idx, j + q);
      const uint4 v0 = g4[(size_t)i0 * 16 + c];
      ACC8(v0);
    }
    if (j < cnt) {
      const int rem = cnt - j;  // 1..3 leftover rows
      const int i0 = __shfl(idx, j + min(q, rem - 1));
      if (q < rem) {
        const uint4 v0 = g4[(size_t)i0 * 16 + c];
        ACC8(v0);
      }
    }
  }
#pragma unroll
  for (int k = 0; k < 8; ++k) {
    acc[k] += __shfl_xor(acc[k], 16);
    acc[k] += __shfl_xor(acc[k], 32);
  }
  if (l < 16) {
    const float inv = 1.0f / fmaxf((float)(e - s), 1.0f);
    const float4 r0 = ((const float4*)r)[(size_t)n * 32 + c * 2 + 0];
    const float4 r1 = ((const float4*)r)[(size_t)n * 32 + c * 2 + 1];
    float4 o0, o1;
    o0.x = fmaf(acc[0], inv, r0.x);
    o0.y = fmaf(acc[1], inv, r0.y);
    o0.z = fmaf(acc[2], inv, r0.z);
    o0.w = fmaf(acc[3], inv, r0.w);
    o1.x = fmaf(acc[4], inv, r1.x);
    o1.y = fmaf(acc[5], inv, r1.y);
    o1.z = fmaf(acc[6], inv, r1.z);
    o1.w = fmaf(acc[7], inv, r1.w);
    ((float4*)out)[(size_t)n * 32 + c * 2 + 0] = o0;
    ((float4*)out)[(size_t)n * 32 + c * 2 + 1] = o1;
  }
}

// ---------------------------------------------------------------------------
extern "C" void kernel_launch(void* const* d_in, const int* in_sizes, int n_in,
                              void* d_out, int out_size, void* d_ws,
                              size_t ws_size, hipStream_t stream) {
  const float* x = (const float*)d_in[0];
  const int* ei = (const int*)d_in[1];  // [2,E] flat: src [0,E), dst [E,2E)
  const float* mask = (const float*)d_in[2];
  const float* gamma = (const float*)d_in[3];
  const float* beta = (const float*)d_in[4];
  const float* w_l = (const float*)d_in[5];
  const float* b_l = (const float*)d_in[6];
  const float* w_r = (const float*)d_in[7];
  float* out = (float*)d_out;

  char* ws = (char*)d_ws;
  size_t off = 0;
  auto alloc = [&](size_t bytes) {
    char* p = ws + off;
    off += (bytes + 255) & ~(size_t)255;
    return p;
  };
  unsigned int* hb =
      (unsigned int*)alloc((size_t)N_NODES * D * sizeof(unsigned short));
  unsigned int* gb =
      (unsigned int*)alloc((size_t)N_NODES * D * sizeof(unsigned short));
  float* r = (float*)alloc((size_t)N_NODES * D * sizeof(float));
  unsigned int* wtb =
      (unsigned int*)alloc((size_t)2 * D * D * sizeof(unsigned short));
  int* deg = (int*)alloc((size_t)N_NODES * sizeof(int));
  int* offsets = (int*)alloc((size_t)(N_NODES + 1) * sizeof(int));
  int* partial = (int*)alloc((size_t)NB_SCAN * sizeof(int));
  int* rank = (int*)alloc((size_t)N_EDGES * sizeof(int));
  int* csr = (int*)alloc((size_t)N_EDGES * sizeof(int));

  hipMemsetAsync(deg, 0, (size_t)N_NODES * sizeof(int), stream);
  wt_kernel<<<64, 256, 0, stream>>>(w_l, w_r, wtb);
  ln_kernel<<<N_NODES / 4, 256, 0, stream>>>(x, mask, gamma, beta, hb);
  gemm_kernel<<<dim3((N_NODES + 63) / 64, 4), 256, 0, stream>>>(
      (const unsigned short*)hb, (const unsigned short*)wtb, b_l, gb, r);
  hist_kernel<<<N_EDGES / 256, 256, 0, stream>>>(ei, deg, rank);
  scan1_kernel<<<NB_SCAN, 256, 0, stream>>>(deg, offsets, partial);
  scan2_kernel<<<1, 256, 0, stream>>>(partial);
  scan3_kernel<<<NB_SCAN, 256, 0, stream>>>(offsets, partial);
  scatter_kernel<<<N_EDGES / 256, 256, 0, stream>>>(ei, offsets, rank, csr);
  agg_kernel<<<N_NODES / 4, 256, 0, stream>>>(offsets, csr, gb, r, out);
}

// Round 6
// 218.856 us; speedup vs baseline: 1.8986x; 1.0978x over previous
//
#include <hip/hip_runtime.h>
#include <hip/hip_bf16.h>

#define N_NODES 50000
#define N_EDGES 800000
#define D 128
#define NB_SCAN ((N_NODES + 255) / 256)  // 196

typedef short bf16x8 __attribute__((ext_vector_type(8)));
typedef float f32x4 __attribute__((ext_vector_type(4)));

__device__ __forceinline__ unsigned int bf16u(float f) {
  __hip_bfloat16 b = __float2bfloat16(f);
  return (unsigned int)*reinterpret_cast<unsigned short*>(&b);
}

// ---------------------------------------------------------------------------
// LayerNorm + ReLU + dropout-mask -> bf16 h.  One wave per node, float2/lane.
// ---------------------------------------------------------------------------
__global__ __launch_bounds__(256) void ln_kernel(
    const float* __restrict__ x, const float* __restrict__ mask,
    const float* __restrict__ gamma, const float* __restrict__ beta,
    unsigned int* __restrict__ hb) {
  const int l = threadIdx.x & 63;
  const int n = blockIdx.x * 4 + (threadIdx.x >> 6);
  const float2 xv = ((const float2*)x)[(size_t)n * 64 + l];
  float s = xv.x + xv.y;
  float q = xv.x * xv.x + xv.y * xv.y;
#pragma unroll
  for (int m = 1; m < 64; m <<= 1) {
    s += __shfl_xor(s, m);
    q += __shfl_xor(q, m);
  }
  const float mean = s * (1.0f / 128.0f);
  const float var = q * (1.0f / 128.0f) - mean * mean;
  const float rs = rsqrtf(var + 1e-5f);
  const float2 gv = ((const float2*)gamma)[l];
  const float2 bv = ((const float2*)beta)[l];
  const float2 mv = ((const float2*)mask)[(size_t)n * 64 + l];
  const float h0 = fmaxf((xv.x - mean) * rs * gv.x + bv.x, 0.0f) * mv.x;
  const float h1 = fmaxf((xv.y - mean) * rs * gv.y + bv.y, 0.0f) * mv.y;
  hb[(size_t)n * 64 + l] = (bf16u(h1) << 16) | bf16u(h0);
}

// ---------------------------------------------------------------------------
// Cast stacked weights to bf16 row-major [256][128]: rows 0..127 = w_l,
// rows 128..255 = w_r.
// ---------------------------------------------------------------------------
__global__ __launch_bounds__(256) void wt_kernel(
    const float* __restrict__ w_l, const float* __restrict__ w_r,
    unsigned int* __restrict__ wtb) {
  const int i = blockIdx.x * 256 + threadIdx.x;  // 0..16383 (uint = 2 bf16)
  const float* src = (i < 8192) ? w_l : w_r;
  const int j = (i < 8192) ? 2 * i : 2 * (i - 8192);
  wtb[i] = (bf16u(src[j + 1]) << 16) | bf16u(src[j]);
}

// ---------------------------------------------------------------------------
// MFMA GEMM: [g | r](permuted cols) = h_bf16 @ [w_l | w_r]^T_bf16 (+b_l on r).
// Block = 4 waves = 64 nodes x 256 outs; grid 782.  Wave: 16 nodes x 256 outs
// = 64 x mfma_f32_16x16x32_bf16.  B staged once per block into LDS in MFMA
// fragment order (lane-consecutive 16B => conflict-free); A frags direct from
// global; NO output transpose: store layout s = (col&15)*8 + (col>>4), i.e.
// lane lm's acc[sub][reg] for node m goes to short index lm*8+sub of row m.
// agg un-permutes in its epilogue.
// A[m=lane&15][k=quad*8+j]; B-frag = 8 k-elems of out-row n; D[m=quad*4+reg][n=lane&15].
// ---------------------------------------------------------------------------
__global__ __launch_bounds__(256) void gemm_kernel(
    const unsigned short* __restrict__ hb,
    const unsigned short* __restrict__ wtb, const float* __restrict__ b_l,
    unsigned int* __restrict__ gb, float* __restrict__ rp) {
  __shared__ unsigned short Bs[64 * 64 * 8];  // 64 frags x 64 lanes x 8 bf16
  const int t = threadIdx.x;
  const int w = t >> 6;
  const int l = t & 63;
  const int lm = l & 15;
  const int quad = l >> 4;
  const int nb = blockIdx.x * 64;

  // A fragments: node = nb + w*16 + lm, k = ch*32 + quad*8 (+0..7)
  int anode = nb + w * 16 + lm;
  if (anode >= N_NODES) anode = N_NODES - 1;  // clamped read; stores guarded
  const unsigned short* arow = hb + (size_t)anode * D + quad * 8;
  bf16x8 af[4];
#pragma unroll
  for (int ch = 0; ch < 4; ++ch) af[ch] = *(const bf16x8*)(arow + ch * 32);

  // Stage B into fragment-ordered LDS: frag fid=(sub,ch) holds, at lane l,
  // wtb[row = sub*16+lm][k = ch*32 + quad*8 .. +8].
#pragma unroll
  for (int i = 0; i < 16; ++i) {
    const int fid = w * 16 + i;
    const int sub = fid >> 2;
    const int ch = fid & 3;
    const uint4 v = *(const uint4*)(wtb + (size_t)(sub * 16 + lm) * D +
                                    ch * 32 + quad * 8);
    *(uint4*)(Bs + ((size_t)fid * 64 + l) * 8) = v;
  }
  __syncthreads();

  f32x4 acc[16];
#pragma unroll
  for (int sub = 0; sub < 16; ++sub) acc[sub] = (f32x4){0.f, 0.f, 0.f, 0.f};
  const bf16x8* BsF = (const bf16x8*)Bs;
#pragma unroll
  for (int sub = 0; sub < 16; ++sub)
#pragma unroll
    for (int ch = 0; ch < 4; ++ch)
      acc[sub] = __builtin_amdgcn_mfma_f32_16x16x32_bf16(
          af[ch], BsF[(sub * 4 + ch) * 64 + l], acc[sub], 0, 0, 0);

  // Epilogue (no LDS): bias values this lane needs: b_l[j*16 + lm], j=0..7.
  float blv[8];
#pragma unroll
  for (int j = 0; j < 8; ++j) blv[j] = b_l[j * 16 + lm];

  const int node0 = nb + w * 16 + quad * 4;
#pragma unroll
  for (int reg = 0; reg < 4; ++reg) {
    const int node = node0 + reg;
    if (node < N_NODES) {
      // g half (subs 0..7): pack 8 bf16 -> uint4 at short-offset lm*8.
      uint4 p;
      p.x = (bf16u(acc[1][reg]) << 16) | bf16u(acc[0][reg]);
      p.y = (bf16u(acc[3][reg]) << 16) | bf16u(acc[2][reg]);
      p.z = (bf16u(acc[5][reg]) << 16) | bf16u(acc[4][reg]);
      p.w = (bf16u(acc[7][reg]) << 16) | bf16u(acc[6][reg]);
      ((uint4*)gb)[(size_t)node * 16 + lm] = p;
      // r half (subs 8..15): fp32 + bias, float-offset lm*8, 2 x float4.
      float4 q0, q1;
      q0.x = acc[8][reg] + blv[0];
      q0.y = acc[9][reg] + blv[1];
      q0.z = acc[10][reg] + blv[2];
      q0.w = acc[11][reg] + blv[3];
      q1.x = acc[12][reg] + blv[4];
      q1.y = acc[13][reg] + blv[5];
      q1.z = acc[14][reg] + blv[6];
      q1.w = acc[15][reg] + blv[7];
      ((float4*)rp)[(size_t)node * 32 + lm * 2 + 0] = q0;
      ((float4*)rp)[(size_t)node * 32 + lm * 2 + 1] = q1;
    }
  }
}

// ---------------------------------------------------------------------------
// CSR build: degree histogram (capturing per-edge rank) -> 2-level scan
// (final offsets computed on the fly by consumers) -> atomic-free scatter.
// ---------------------------------------------------------------------------
__global__ __launch_bounds__(256) void hist_kernel(const int* __restrict__ ei,
                                                   int* __restrict__ deg,
                                                   int* __restrict__ rank) {
  const int e = (blockIdx.x * 256 + threadIdx.x) * 4;
  if (e + 3 < N_EDGES) {
    const int4 d4 = *(const int4*)(ei + N_EDGES + e);
    int4 r4;
    r4.x = atomicAdd(&deg[d4.x], 1);
    r4.y = atomicAdd(&deg[d4.y], 1);
    r4.z = atomicAdd(&deg[d4.z], 1);
    r4.w = atomicAdd(&deg[d4.w], 1);
    *(int4*)(rank + e) = r4;
  } else {
    for (int k = e; k < N_EDGES; ++k)
      rank[k] = atomicAdd(&deg[ei[N_EDGES + k]], 1);
  }
}

// Stage 1: per-block (256-wide) exclusive scan + block totals.
__global__ __launch_bounds__(256) void scan1_kernel(
    const int* __restrict__ deg, int* __restrict__ offL1,
    int* __restrict__ partial) {
  __shared__ int sm[256];
  const int t = threadIdx.x;
  const int i = blockIdx.x * 256 + t;
  const int v = (i < N_NODES) ? deg[i] : 0;
  sm[t] = v;
  __syncthreads();
#pragma unroll
  for (int ofs = 1; ofs < 256; ofs <<= 1) {
    int x = sm[t];
    if (t >= ofs) x += sm[t - ofs];
    __syncthreads();
    sm[t] = x;
    __syncthreads();
  }
  if (i < N_NODES) offL1[i] = sm[t] - v;
  if (t == 255) partial[blockIdx.x] = sm[255];
}

// Stage 2: exclusive scan of the 196 block totals (in place).
__global__ __launch_bounds__(256) void scan2_kernel(int* __restrict__ partial) {
  __shared__ int sm[256];
  const int t = threadIdx.x;
  const int v = (t < NB_SCAN) ? partial[t] : 0;
  sm[t] = v;
  __syncthreads();
#pragma unroll
  for (int ofs = 1; ofs < 256; ofs <<= 1) {
    int x = sm[t];
    if (t >= ofs) x += sm[t - ofs];
    __syncthreads();
    sm[t] = x;
    __syncthreads();
  }
  if (t < NB_SCAN) partial[t] = sm[t] - v;
}

__global__ __launch_bounds__(256) void scatter_kernel(
    const int* __restrict__ ei, const int* __restrict__ offL1,
    const int* __restrict__ partial, const int* __restrict__ rank,
    int* __restrict__ csr) {
  const int e = (blockIdx.x * 256 + threadIdx.x) * 4;
  if (e + 3 < N_EDGES) {
    const int4 s4 = *(const int4*)(ei + e);
    const int4 d4 = *(const int4*)(ei + N_EDGES + e);
    const int4 r4 = *(const int4*)(rank + e);
    csr[offL1[d4.x] + partial[d4.x >> 8] + r4.x] = s4.x;
    csr[offL1[d4.y] + partial[d4.y >> 8] + r4.y] = s4.y;
    csr[offL1[d4.z] + partial[d4.z >> 8] + r4.z] = s4.z;
    csr[offL1[d4.w] + partial[d4.w >> 8] + r4.w] = s4.w;
  } else {
    for (int k = e; k < N_EDGES; ++k) {
      const int dst = ei[N_EDGES + k];
      csr[offL1[dst] + partial[dst >> 8] + rank[k]] = ei[k];
    }
  }
}

// ---------------------------------------------------------------------------
// Mean-aggregate bf16 g rows (permuted layout) per dst node, + r -> out.
// One wave per node; 4 rows per vmem instruction (quarter-wave x uint4).
// Lane c's uint4 chunk holds cols {j*16+c, j=0..7}; epilogue un-permutes.
// ---------------------------------------------------------------------------
#define ACC8(v)                                     \
  do {                                              \
    acc[0] += __uint_as_float((v).x << 16);         \
    acc[1] += __uint_as_float((v).x & 0xffff0000u); \
    acc[2] += __uint_as_float((v).y << 16);         \
    acc[3] += __uint_as_float((v).y & 0xffff0000u); \
    acc[4] += __uint_as_float((v).z << 16);         \
    acc[5] += __uint_as_float((v).z & 0xffff0000u); \
    acc[6] += __uint_as_float((v).w << 16);         \
    acc[7] += __uint_as_float((v).w & 0xffff0000u); \
  } while (0)

__global__ __launch_bounds__(256) void agg_kernel(
    const int* __restrict__ offL1, const int* __restrict__ partial,
    const int* __restrict__ csr, const unsigned int* __restrict__ gb,
    const float* __restrict__ rp, float* __restrict__ out) {
  const int l = threadIdx.x & 63;
  const int q = l >> 4;  // row within group of 4
  const int c = l & 15;  // 16B chunk within the 256B bf16 row
  const int n = blockIdx.x * 4 + (threadIdx.x >> 6);
  const int s = offL1[n] + partial[n >> 8];
  const int e = (n + 1 < N_NODES) ? offL1[n + 1] + partial[(n + 1) >> 8]
                                  : N_EDGES;
  const uint4* g4 = (const uint4*)gb;
  float acc[8];
#pragma unroll
  for (int k = 0; k < 8; ++k) acc[k] = 0.0f;
  for (int base = s; base < e; base += 64) {
    const int cnt = min(e - base, 64);
    int idx = (l < cnt) ? csr[base + l] : 0;
    int j = 0;
    for (; j + 16 <= cnt; j += 16) {
      const int i0 = __shfl(idx, j + 0 + q);
      const int i1 = __shfl(idx, j + 4 + q);
      const int i2 = __shfl(idx, j + 8 + q);
      const int i3 = __shfl(idx, j + 12 + q);
      const uint4 v0 = g4[(size_t)i0 * 16 + c];
      const uint4 v1 = g4[(size_t)i1 * 16 + c];
      const uint4 v2 = g4[(size_t)i2 * 16 + c];
      const uint4 v3 = g4[(size_t)i3 * 16 + c];
      ACC8(v0);
      ACC8(v1);
      ACC8(v2);
      ACC8(v3);
    }
    for (; j + 4 <= cnt; j += 4) {
      const int i0 = __shfl(idx, j + q);
      const uint4 v0 = g4[(size_t)i0 * 16 + c];
      ACC8(v0);
    }
    if (j < cnt) {
      const int rem = cnt - j;  // 1..3 leftover rows
      const int i0 = __shfl(idx, j + min(q, rem - 1));
      if (q < rem) {
        const uint4 v0 = g4[(size_t)i0 * 16 + c];
        ACC8(v0);
      }
    }
  }
#pragma unroll
  for (int k = 0; k < 8; ++k) {
    acc[k] += __shfl_xor(acc[k], 16);
    acc[k] += __shfl_xor(acc[k], 32);
  }
  if (l < 16) {
    const float inv = 1.0f / fmaxf((float)(e - s), 1.0f);
    // rp holds this lane's 8 values contiguously (same permuted layout).
    const float4 rp0 = ((const float4*)rp)[(size_t)n * 32 + c * 2 + 0];
    const float4 rp1 = ((const float4*)rp)[(size_t)n * 32 + c * 2 + 1];
    float* o = out + (size_t)n * D + c;  // col j*16 + c, stride-16 stores
    o[0]   = fmaf(acc[0], inv, rp0.x);
    o[16]  = fmaf(acc[1], inv, rp0.y);
    o[32]  = fmaf(acc[2], inv, rp0.z);
    o[48]  = fmaf(acc[3], inv, rp0.w);
    o[64]  = fmaf(acc[4], inv, rp1.x);
    o[80]  = fmaf(acc[5], inv, rp1.y);
    o[96]  = fmaf(acc[6], inv, rp1.z);
    o[112] = fmaf(acc[7], inv, rp1.w);
  }
}

// ---------------------------------------------------------------------------
extern "C" void kernel_launch(void* const* d_in, const int* in_sizes, int n_in,
                              void* d_out, int out_size, void* d_ws,
                              size_t ws_size, hipStream_t stream) {
  const float* x = (const float*)d_in[0];
  const int* ei = (const int*)d_in[1];  // [2,E] flat: src [0,E), dst [E,2E)
  const float* mask = (const float*)d_in[2];
  const float* gamma = (const float*)d_in[3];
  const float* beta = (const float*)d_in[4];
  const float* w_l = (const float*)d_in[5];
  const float* b_l = (const float*)d_in[6];
  const float* w_r = (const float*)d_in[7];
  float* out = (float*)d_out;

  char* ws = (char*)d_ws;
  size_t off = 0;
  auto alloc = [&](size_t bytes) {
    char* p = ws + off;
    off += (bytes + 255) & ~(size_t)255;
    return p;
  };
  unsigned int* hb =
      (unsigned int*)alloc((size_t)N_NODES * D * sizeof(unsigned short));
  unsigned int* gb =
      (unsigned int*)alloc((size_t)N_NODES * D * sizeof(unsigned short));
  float* rp = (float*)alloc((size_t)N_NODES * D * sizeof(float));
  unsigned int* wtb =
      (unsigned int*)alloc((size_t)2 * D * D * sizeof(unsigned short));
  int* deg = (int*)alloc((size_t)N_NODES * sizeof(int));
  int* offL1 = (int*)alloc((size_t)N_NODES * sizeof(int));
  int* partial = (int*)alloc((size_t)NB_SCAN * sizeof(int));
  int* rank = (int*)alloc((size_t)N_EDGES * sizeof(int));
  int* csr = (int*)alloc((size_t)N_EDGES * sizeof(int));

  hipMemsetAsync(deg, 0, (size_t)N_NODES * sizeof(int), stream);
  wt_kernel<<<64, 256, 0, stream>>>(w_l, w_r, wtb);
  ln_kernel<<<N_NODES / 4, 256, 0, stream>>>(x, mask, gamma, beta, hb);
  gemm_kernel<<<(N_NODES + 63) / 64, 256, 0, stream>>>(
      (const unsigned short*)hb, (const unsigned short*)wtb, b_l, gb, rp);
  hist_kernel<<<(N_EDGES / 4 + 255) / 256, 256, 0, stream>>>(ei, deg, rank);
  scan1_kernel<<<NB_SCAN, 256, 0, stream>>>(deg, offL1, partial);
  scan2_kernel<<<1, 256, 0, stream>>>(partial);
  scatter_kernel<<<(N_EDGES / 4 + 255) / 256, 256, 0, stream>>>(
      ei, offL1, partial, rank, csr);
  agg_kernel<<<N_NODES / 4, 256, 0, stream>>>(offL1, partial, csr, gb, rp,
                                              out);
}